// Round 16
// baseline (873.277 us; speedup 1.0000x reference)
//
#include <hip/hip_runtime.h>
#include <stdint.h>

#define B_    64
#define C_    3
#define H_    224
#define W_    224
#define P_    16
#define GH_   14
#define NP_   196
#define NPP2_ 256          // AV contraction dim padded to 256 (BK=64 friendly)
#define PD_   768
#define HEADS_ 8
#define VDIM_ 128
#define DIM_  1024
#define DEPTH_ 6
#define NC_   1000
#define EPS_  1e-5f
#define SCALE_ 0.08838834764831845f   // 128^-0.5
#define ROWS_ (B_*NP_)                 // 12544
#define FTS2_ ((size_t)DIM_ * NPP2_)   // fwT per-batch stride (262144)
#define APS2_ ((size_t)224 * NPP2_)    // A_pad per-batch stride (57344)
#define XS_   ((size_t)NP_ * DIM_)     // h/t/x per-batch stride

typedef __bf16 bf16;
typedef __bf16 bfv8 __attribute__((ext_vector_type(8)));
typedef __bf16 bfv4 __attribute__((ext_vector_type(4)));
typedef float  f32x4 __attribute__((ext_vector_type(4)));

#define AS1 __attribute__((address_space(1)))
#define AS3 __attribute__((address_space(3)))

__device__ __forceinline__ void gld_lds16(const bf16* g, bf16* l) {
    __builtin_amdgcn_global_load_lds((const AS1 uint32_t*)g, (AS3 uint32_t*)l, 16, 0, 0);
}

__device__ __forceinline__ f32x4 mfma16(bfv8 a, bfv8 b, f32x4 c) {
    return __builtin_amdgcn_mfma_f32_16x16x32_bf16(a, b, c, 0, 0, 0);
}

// ---------------- zero-fill (float4 grid-stride) -----------------------------
__global__ void zero_f4(float4* __restrict__ p, size_t n4) {
    size_t i = (size_t)blockIdx.x * blockDim.x + threadIdx.x;
    size_t stride = (size_t)gridDim.x * blockDim.x;
    float4 z = {0.f, 0.f, 0.f, 0.f};
    for (; i < n4; i += stride) p[i] = z;
}

// ---------------- fp32 -> bf16 elementwise convert (x4 per thread) -----------
__global__ void conv_bf16(const float* __restrict__ in, bf16* __restrict__ out,
                          size_t n4) {
    size_t i = (size_t)blockIdx.x * blockDim.x + threadIdx.x;
    size_t stride = (size_t)gridDim.x * blockDim.x;
    for (; i < n4; i += stride) {
        float4 v = ((const float4*)in)[i];
        bfv4 o = { (bf16)v.x, (bf16)v.y, (bf16)v.z, (bf16)v.w };
        *(bfv4*)(out + i * 4) = o;
    }
}

// ---------------- block-wide twin reduction (patchify only) ------------------
__device__ inline void block_reduce_2(float& a, float& b) {
    __shared__ float sa[4], sb[4];
    #pragma unroll
    for (int o = 32; o > 0; o >>= 1) {
        a += __shfl_down(a, o);
        b += __shfl_down(b, o);
    }
    int lane = threadIdx.x & 63, wid = threadIdx.x >> 6;
    if (lane == 0) { sa[wid] = a; sb[wid] = b; }
    __syncthreads();
    a = sa[0] + sa[1] + sa[2] + sa[3];
    b = sb[0] + sb[1] + sb[2] + sb[3];
    __syncthreads();
}

// ---------------- patchify + LayerNorm over PD=768 -> bf16 -------------------
__global__ void patchify_ln(const float* __restrict__ img,
                            const float* __restrict__ g,
                            const float* __restrict__ beta,
                            bf16* __restrict__ out) {
    int bn = blockIdx.x;
    int b = bn / NP_, n = bn % NP_;
    int gh = n / GH_, gw = n % GH_;
    int t = threadIdx.x;              // pixel 0..255
    int p1 = t >> 4, p2 = t & 15;
    int row = gh * P_ + p1, col = gw * P_ + p2;
    const float* ip = img + (size_t)b * C_ * H_ * W_ + (size_t)row * W_ + col;
    float v0 = ip[0];
    float v1 = ip[H_ * W_];
    float v2 = ip[2 * H_ * W_];
    float s  = v0 + v1 + v2;
    float s2 = v0 * v0 + v1 * v1 + v2 * v2;
    block_reduce_2(s, s2);
    float mean = s * (1.0f / PD_);
    float var  = s2 * (1.0f / PD_) - mean * mean;
    float r = rsqrtf(var + EPS_);
    int d = t * 3;
    bf16* op = out + (size_t)bn * PD_ + d;
    op[0] = (bf16)((v0 - mean) * r * g[d]     + beta[d]);
    op[1] = (bf16)((v1 - mean) * r * g[d + 1] + beta[d + 1]);
    op[2] = (bf16)((v2 - mean) * r * g[d + 2] + beta[d + 2]);
}

// ---------------- row LayerNorm over DIM=1024: WAVE-PER-ROW, XCD-clustered ---
// (r10-proven math; r16 adds the same residue mapping as av/sfw/softmax so
// x[z] is READ from, and h[z] WRITTEN to, XCD z%8's L2 — completing the
// av -> x -> ln -> h -> sfw per-batch L2 chain. 3136 blocks = 8 xcd x
// 8 batch-groups x 49 row-chunks of 4. Heuristic only; math identical.)
__global__ void ln_rows(const bf16* __restrict__ in,
                        bf16* __restrict__ outb,
                        const float* __restrict__ g, const float* __restrict__ beta,
                        const float* __restrict__ pos) {
    int b = blockIdx.x;                  // 3136
    int xcd = b & 7, idx = b >> 3;       // idx in [0,392)
    int z = xcd + 8 * (idx / 49);        // batch
    int rblk = idx % 49;                 // 4-row chunk within batch
    int wave = threadIdx.x >> 6, lane = threadIdx.x & 63;
    int r = z * NP_ + rblk * 4 + wave;   // global row
    const bf16* ip = in + (size_t)r * DIM_;
    float4 v[4];
    float s = 0.f, s2 = 0.f;
    #pragma unroll
    for (int i = 0; i < 4; i++) {
        bfv4 iv = *(const bfv4*)(ip + lane * 4 + i * 256);
        v[i].x = (float)iv[0]; v[i].y = (float)iv[1];
        v[i].z = (float)iv[2]; v[i].w = (float)iv[3];
        s  += v[i].x + v[i].y + v[i].z + v[i].w;
        s2 += v[i].x * v[i].x + v[i].y * v[i].y
            + v[i].z * v[i].z + v[i].w * v[i].w;
    }
    #pragma unroll
    for (int o = 32; o > 0; o >>= 1) {
        s  += __shfl_xor(s, o);
        s2 += __shfl_xor(s2, o);
    }
    float mean = s * (1.0f / DIM_);
    float var  = s2 * (1.0f / DIM_) - mean * mean;
    float rs = rsqrtf(var + EPS_);
    int n = r % NP_;
    bf16* op = outb + (size_t)r * DIM_;
    #pragma unroll
    for (int i = 0; i < 4; i++) {
        int idx4 = lane + i * 64;                // float4 index into g/beta/pos
        float4 gv = ((const float4*)g)[idx4];
        float4 bv = ((const float4*)beta)[idx4];
        float4 o;
        o.x = (v[i].x - mean) * rs * gv.x + bv.x;
        o.y = (v[i].y - mean) * rs * gv.y + bv.y;
        o.z = (v[i].z - mean) * rs * gv.z + bv.z;
        o.w = (v[i].w - mean) * rs * gv.w + bv.w;
        if (pos) {
            float4 pv = ((const float4*)(pos + (size_t)n * DIM_))[idx4];
            o.x += pv.x; o.y += pv.y; o.z += pv.z; o.w += pv.w;
        }
        bfv4 ob = { (bf16)o.x, (bf16)o.y, (bf16)o.z, (bf16)o.w };
        *(bfv4*)(op + lane * 4 + i * 256) = ob;
    }
}

// ---------------- 128x64-tile MFMA GEMM, BK=64, swizzled LDS -----------------
// (round-1 single-buffer version — measured ~640 TF. QK + stem + WqkT prep.)
template<bool OUT_BF16>
__global__ __launch_bounds__(256)
void gemm_bt_m128n64k64(const bf16* __restrict__ A, const bf16* __restrict__ BT,
                        void* __restrict__ Cout, const float* __restrict__ bias,
                        int M, int N, int K) {
    __shared__ bf16 Asm[128 * 64];   // 16 KB
    __shared__ bf16 Bsm[64 * 64];    //  8 KB
    const int tid = threadIdx.x;
    const int wave = tid >> 6, lane = tid & 63;
    const int MT = gridDim.y, NT = gridDim.x;
    const int flat = blockIdx.y * NT + blockIdx.x;
    const int per = 8 * NT;
    const int group = flat / per;
    const int within = flat % per;
    int gm = MT - group * 8; if (gm > 8) gm = 8;
    const int m0 = (group * 8 + within % gm) * 128;
    const int n0 = (within / gm) * 64;
    const int r8 = lane >> 3;
    const int cl = lane & 7;
    const int kg = (cl ^ r8) * 8;
    const bf16* Ag = A  + (size_t)(m0 + wave * 32 + r8) * K + kg;
    const bf16* Bg = BT + (size_t)(n0 + wave * 16 + r8) * K + kg;
    bf16* Al = Asm + wave * 2048;        // 32 rows x 64
    bf16* Bl = Bsm + wave * 1024;        // 16 rows x 64
    const int qd = lane >> 4, l15 = lane & 15;
    const int wm = (wave >> 1) * 64, wn = (wave & 1) * 32;
    f32x4 acc[4][2] = {};
    for (int k0 = 0; k0 < K; k0 += 64) {
        gld_lds16(Ag + k0,                 Al);
        gld_lds16(Ag + (size_t) 8 * K + k0, Al + 512);
        gld_lds16(Ag + (size_t)16 * K + k0, Al + 1024);
        gld_lds16(Ag + (size_t)24 * K + k0, Al + 1536);
        gld_lds16(Bg + k0,                 Bl);
        gld_lds16(Bg + (size_t) 8 * K + k0, Bl + 512);
        __syncthreads();
        bfv8 a0[4], a1[4], b0[2], b1[2];
        #pragma unroll
        for (int i = 0; i < 4; i++) {
            int R = wm + i * 16 + l15, sw = R & 7;
            a0[i] = *(const bfv8*)(Asm + R * 64 + ((qd    ) ^ sw) * 8);
            a1[i] = *(const bfv8*)(Asm + R * 64 + ((qd + 4) ^ sw) * 8);
        }
        #pragma unroll
        for (int j = 0; j < 2; j++) {
            int R = wn + j * 16 + l15, sw = R & 7;
            b0[j] = *(const bfv8*)(Bsm + R * 64 + ((qd    ) ^ sw) * 8);
            b1[j] = *(const bfv8*)(Bsm + R * 64 + ((qd + 4) ^ sw) * 8);
        }
        #pragma unroll
        for (int i = 0; i < 4; i++)
            #pragma unroll
            for (int j = 0; j < 2; j++) {
                acc[i][j] = mfma16(a0[i], b0[j], acc[i][j]);
                acc[i][j] = mfma16(a1[i], b1[j], acc[i][j]);
            }
        __syncthreads();
    }
    float* Cf = (float*)Cout;
    bf16*  Cb = (bf16*)Cout;
    #pragma unroll
    for (int i = 0; i < 4; i++) {
        int rowb = m0 + wm + i * 16 + qd * 4;
        #pragma unroll
        for (int j = 0; j < 2; j++) {
            int col = n0 + wn + j * 16 + l15;
            float bv = bias ? bias[col] : 0.0f;
            #pragma unroll
            for (int r = 0; r < 4; r++) {
                float v = acc[i][j][r] + bv;
                if (OUT_BF16) Cb[(size_t)(rowb + r) * N + col] = (bf16)v;
                else          Cf[(size_t)(rowb + r) * N + col] = v;
            }
        }
    }
}

// ---------------- small MFMA GEMM body: 64x64 tile, BK=64 --------------------
// (round-1-proven single-buffer structure, shared by all small-GEMM launchers.
// r14's 128-row-tile variant regressed even L2-hot — 64² + max block TLP is
// the confirmed optimum for these shapes; do not revisit.)
template<bool OUT_BF16>
__device__ __forceinline__ void small64_body(
        const bf16* __restrict__ A, long lda,
        const bf16* __restrict__ BT, long ldb,
        void* __restrict__ Cout, long ldc,
        const float* __restrict__ bias,
        const bf16* __restrict__ rs,
        int M, int N, int K, float alpha,
        int m0, int n0) {
    __shared__ bf16 Asm[64 * 64];
    __shared__ bf16 Bsm[64 * 64];
    const int tid = threadIdx.x;
    const int wave = tid >> 6, lane = tid & 63;
    const int r8 = lane >> 3;            // 0..7: row within 8-row staging group
    const int cl = lane & 7;             // LDS chunk within row
    const int kg = (cl ^ r8) * 8;        // global k-offset (bf16) for this lane
    const int qd = lane >> 4, l15 = lane & 15;
    const bf16* Ag0 = A  + (size_t)(m0 + wave * 16 + r8) * lda + kg;
    const bf16* Ag1 = Ag0 + (size_t)8 * lda;
    const bf16* Bg0 = BT + (size_t)(n0 + wave * 16 + r8) * ldb + kg;
    const bf16* Bg1 = Bg0 + (size_t)8 * ldb;
    bf16* Al0 = Asm + wave * 1024;       // 16 rows x 64
    bf16* Al1 = Al0 + 512;               // +8 rows
    bf16* Bl0 = Bsm + wave * 1024;
    bf16* Bl1 = Bl0 + 512;
    f32x4 acc[4] = {};
    for (int k0 = 0; k0 < K; k0 += 64) {
        gld_lds16(Ag0 + k0, Al0);
        gld_lds16(Ag1 + k0, Al1);
        gld_lds16(Bg0 + k0, Bl0);
        gld_lds16(Bg1 + k0, Bl1);
        __syncthreads();
        int RA = wave * 16 + l15, swa = RA & 7;
        bfv8 af0 = *(const bfv8*)(Asm + RA * 64 + ((qd    ) ^ swa) * 8);
        bfv8 af1 = *(const bfv8*)(Asm + RA * 64 + ((qd + 4) ^ swa) * 8);
        #pragma unroll
        for (int j = 0; j < 4; j++) {
            int R = j * 16 + l15, sw = R & 7;
            bfv8 b0 = *(const bfv8*)(Bsm + R * 64 + ((qd    ) ^ sw) * 8);
            bfv8 b1 = *(const bfv8*)(Bsm + R * 64 + ((qd + 4) ^ sw) * 8);
            acc[j] = mfma16(af0, b0, acc[j]);
            acc[j] = mfma16(af1, b1, acc[j]);
        }
        __syncthreads();
    }
    float* Cf = (float*)Cout;
    bf16*  Cb = (bf16*)Cout;
    #pragma unroll
    for (int j = 0; j < 4; j++) {
        int col = n0 + j * 16 + l15;
        if (col >= N) continue;
        float bv = bias ? bias[col] : 0.f;
        #pragma unroll
        for (int r = 0; r < 4; r++) {
            int row = m0 + wave * 16 + qd * 4 + r;
            if (row >= M) continue;
            float v = alpha * acc[j][r] + bv;
            if (rs) v += (float)rs[(size_t)row * ldc + col];
            if (OUT_BF16) Cb[(size_t)row * ldc + col] = (bf16)v;
            else          Cf[(size_t)row * ldc + col] = v;
        }
    }
}

// ---------------- small MFMA GEMM kernel (classifier) ------------------------
template<bool OUT_BF16>
__global__ __launch_bounds__(256)
void gemm_bt_small64(const bf16* __restrict__ A, long sA1, long sA2, long lda,
                     const bf16* __restrict__ BT, long sB1, long sB2, long ldb,
                     void* __restrict__ Cout, long sC1, long sC2, long ldc,
                     const float* __restrict__ bias,
                     const bf16* __restrict__ resid, long sR1,
                     int M, int N, int K, float alpha, int zdiv) {
    const int bz = blockIdx.z;
    const int z1 = bz / zdiv, z2 = bz % zdiv;
    small64_body<OUT_BF16>(
        A  + (size_t)z1 * sA1 + (size_t)z2 * sA2, lda,
        BT + (size_t)z1 * sB1 + (size_t)z2 * sB2, ldb,
        (void*)((OUT_BF16 ? (void*)((bf16*)Cout + (size_t)z1 * sC1 + (size_t)z2 * sC2)
                          : (void*)((float*)Cout + (size_t)z1 * sC1 + (size_t)z2 * sC2))),
        ldc, bias,
        resid ? resid + (size_t)z1 * sR1 : nullptr,
        M, N, K, alpha,
        blockIdx.y * 64, blockIdx.x * 64);
}

// ---------------- FUSED S + fw launch, XCD-batch-clustered -------------------
// (r13-exact.) xcd = id&7; batch z ≡ xcd mod 8 keeps each batch's t/h panels
// in one XCD L2. Per XCD: 128 S items + 512 fw items.
__global__ __launch_bounds__(256)
void sfw_fused(const bf16* __restrict__ t_bf, const bf16* __restrict__ h_bf,
               float* __restrict__ S, const bf16* __restrict__ WVT,
               bf16* __restrict__ fwT) {
    int b = blockIdx.x;                 // 5120
    int xcd = b & 7, idx = b >> 3;      // idx in [0,640)
    if (idx < 128) {
        // S-gemm: z = xcd + 8*(idx>>4), tile = idx&15 (bx=tile&3, by=tile>>2)
        int z = xcd + 8 * (idx >> 4);
        int tile = idx & 15;
        int bx = tile & 3, by = tile >> 2;
        small64_body<false>(
            t_bf + (size_t)z * XS_, DIM_,
            h_bf + (size_t)z * XS_, DIM_,
            (void*)(S + (size_t)z * (NP_ * NP_)), NP_,
            nullptr, nullptr,
            NP_, NP_, DIM_, SCALE_,
            by * 64, bx * 64);
    } else {
        // fw-gemm: f in [0,512): z1 = xcd + 8*(f>>6); r=f&63: head z2=r>>3,
        // tile t=r&7 (bx=t&3, by=t>>2)
        int f = idx - 128;
        int z1 = xcd + 8 * (f >> 6);
        int r = f & 63;
        int z2 = r >> 3;
        int t = r & 7;
        int bx = t & 3, by = t >> 2;
        small64_body<true>(
            WVT, VDIM_,
            h_bf + (size_t)z1 * XS_ + (size_t)z2 * VDIM_, DIM_,
            (void*)(fwT + (size_t)z1 * FTS2_ + (size_t)z2 * ((size_t)VDIM_ * NPP2_)),
            NPP2_,
            nullptr, nullptr,
            VDIM_, NP_, VDIM_, 1.0f,
            by * 64, bx * 64);
    }
}

// ---------------- AV GEMM launch, XCD-batch-clustered ------------------------
// (r13-exact.) x = A_pad @ fwT^T + h; each batch's 64 tiles on one XCD
// (fwT 512KB + A_pad 112KB L2-hot).
__global__ __launch_bounds__(256)
void av_gemm(const bf16* __restrict__ A_pad, const bf16* __restrict__ fwT,
             bf16* __restrict__ x, const bf16* __restrict__ h_bf) {
    int b = blockIdx.x;                 // 4096
    int xcd = b & 7, idx = b >> 3;      // idx in [0,512)
    int z = xcd + 8 * (idx >> 6);       // batch
    int r = idx & 63;
    int by = r >> 4, bx = r & 15;       // m-tile 0..3, n-tile 0..15
    small64_body<true>(
        A_pad + (size_t)z * APS2_, NPP2_,
        fwT   + (size_t)z * FTS2_, NPP2_,
        (void*)(x + (size_t)z * XS_), DIM_,
        nullptr,
        h_bf + (size_t)z * XS_,
        NP_, DIM_, NPP2_, 1.0f,
        by * 64, bx * 64);
}

// ------- softmax, XCD-batch-clustered: fp32 S -> bf16 A_pad [b][224][256] ----
// (r15-proven.) Same residue mapping as S-producer / A_pad-consumer.
// 832 blocks = 8 xcd x 8 batches x 13 chunks of 16 rows.
__global__ void softmax_pad(const float* __restrict__ S, bf16* __restrict__ Apad) {
    int b = blockIdx.x;                 // 832
    int xcd = b & 7, idx = b >> 3;      // idx in [0,104)
    int z = xcd + 8 * (idx / 13);       // batch
    int c = idx % 13;                   // 16-row chunk
    int wave = threadIdx.x >> 6, lane = threadIdx.x & 63;
    int base = c * 16 + wave * 4;
    const float* Sb = S + (size_t)z * (NP_ * NP_);
    bf16* Pb = Apad + (size_t)z * APS2_;
    #pragma unroll
    for (int i = 0; i < 4; i++) {
        int n = base + i;
        if (n >= NP_) continue;
        const float* Sp = Sb + (size_t)n * NP_;
        float v0 = Sp[lane];
        float v1 = Sp[lane + 64];
        float v2 = Sp[lane + 128];
        float v3 = (lane < NP_ - 192) ? Sp[lane + 192] : -1e30f;
        float mx = fmaxf(fmaxf(v0, v1), fmaxf(v2, v3));
        #pragma unroll
        for (int o = 32; o > 0; o >>= 1) mx = fmaxf(mx, __shfl_xor(mx, o));
        float e0 = __expf(v0 - mx);
        float e1 = __expf(v1 - mx);
        float e2 = __expf(v2 - mx);
        float e3 = (lane < NP_ - 192) ? __expf(v3 - mx) : 0.f;
        float s = e0 + e1 + e2 + e3;
        #pragma unroll
        for (int o = 32; o > 0; o >>= 1) s += __shfl_xor(s, o);
        float inv = 1.0f / s;
        bf16* Pr = Pb + (size_t)n * NPP2_;
        Pr[lane]       = (bf16)(e0 * inv);
        Pr[lane + 64]  = (bf16)(e1 * inv);
        Pr[lane + 128] = (bf16)(e2 * inv);
        int c3 = lane + 192;
        Pr[c3] = (c3 < NP_) ? (bf16)(e3 * inv) : (bf16)0.f;
    }
}

// ---------------- transpose+convert fp32 [R,C] -> bf16 [C,R] -----------------
__global__ void transpose_conv(const float* __restrict__ in, bf16* __restrict__ out,
                               int R, int Cc) {
    __shared__ float t[32][33];
    int c0 = blockIdx.x * 32, r0 = blockIdx.y * 32;
    int tx = threadIdx.x & 31, ty = threadIdx.x >> 5;   // 32 x 8
    #pragma unroll
    for (int i = 0; i < 4; i++) {
        int r = r0 + ty + i * 8;
        if (r < R && c0 + tx < Cc) t[ty + i * 8][tx] = in[(size_t)r * Cc + c0 + tx];
    }
    __syncthreads();
    #pragma unroll
    for (int i = 0; i < 4; i++) {
        int c = c0 + ty + i * 8, r = r0 + tx;
        if (c < Cc && r < R) out[(size_t)c * R + r] = (bf16)t[tx][ty + i * 8];
    }
}

// ---------------- mean-pool over 196 patches: bf16 in -> bf16 out ------------
__global__ void pool_mean(const bf16* __restrict__ x, bf16* __restrict__ pooled) {
    int b = blockIdx.x;
    int d = blockIdx.y * 256 + threadIdx.x;
    const bf16* p = x + (size_t)b * NP_ * DIM_ + d;
    float s = 0.f;
    for (int n = 0; n < NP_; n++) s += (float)p[(size_t)n * DIM_];
    pooled[(size_t)b * DIM_ + d] = (bf16)(s * (1.0f / NP_));
}

// =============================================================================
extern "C" void kernel_launch(void* const* d_in, const int* in_sizes, int n_in,
                              void* d_out, int out_size, void* d_ws, size_t ws_size,
                              hipStream_t stream) {
    const float* image  = (const float*)d_in[0];
    const float* pos    = (const float*)d_in[1];
    const float* ln_p_g = (const float*)d_in[2];
    const float* ln_p_b = (const float*)d_in[3];
    const float* W_emb  = (const float*)d_in[4];
    const float* b_emb  = (const float*)d_in[5];
    const float* ln_e_g = (const float*)d_in[6];
    const float* ln_e_b = (const float*)d_in[7];
    const float* WV     = (const float*)d_in[8];
    const float* WK     = (const float*)d_in[9];
    const float* WQ     = (const float*)d_in[10];
    const float* ln_g   = (const float*)d_in[11];
    const float* ln_b   = (const float*)d_in[12];
    const float* W_last = (const float*)d_in[13];
    const float* b_last = (const float*)d_in[14];
    float* out = (float*)d_out;

    char* p = (char*)d_ws;
    auto alloc = [&](size_t bytes) { char* r = p; p += (bytes + 255) & ~(size_t)255; return r; };
    // x: bf16 residual stream [12544,1024]
    bf16*  x = (bf16*)alloc((size_t)ROWS_ * DIM_ * 2);
    // attention region: S (fp32) | A_pad [64][224][256] | fwT [64][1024][256].
    // Adjacency required: AV A-staging tail (batch 63, m-tile 3) reads <=16KB
    // past A_pad end into fwT (finite; output rows masked).
    char*  region = alloc(9834496 + 7340032 + 33554432);
    float* S     = (float*)region;                              //  9,834,496 B
    bf16*  A_pad = (bf16*)(region + 9834496);                   //  7,340,032 B
    bf16*  fwT   = (bf16*)(region + 9834496 + 7340032);         // 33,554,432 B
    // ORDER AUDIT (gld staging overruns): S-gemm B-tail reads <=123 KB past
    // h_bf (into t_bf); S-gemm A-tail <=123 KB past t_bf (into WembT); fw-gemm
    // B-tail past h_bf (into t_bf); AV A-tail <=16 KB past A_pad (into fwT);
    // classifier N-tail <=49 KB past WlastT (into pooled). Keep this order.
    bf16*  h_bf  = (bf16*)alloc((size_t)ROWS_ * DIM_ * 2);
    bf16*  t_bf  = (bf16*)alloc((size_t)ROWS_ * DIM_ * 2);
    bf16*  WembT  = (bf16*)alloc((size_t)DIM_ * PD_ * 2);
    bf16*  WQ_bf  = (bf16*)alloc((size_t)DIM_ * DIM_ * 2);     // untransposed bf16
    bf16*  WK_bf  = (bf16*)alloc((size_t)DIM_ * DIM_ * 2);
    bf16*  WqkT   = (bf16*)alloc((size_t)DIM_ * DIM_ * 2);     // (WQ WK^T)^T = WK WQ^T
    bf16*  WVT    = (bf16*)alloc((size_t)VDIM_ * VDIM_ * 2);
    bf16*  WlastT = (bf16*)alloc((size_t)NC_ * DIM_ * 2);
    bf16*  pooled = (bf16*)alloc((size_t)B_ * DIM_ * 2);

    // --- weight prep, once per call ------------------------------------------
    transpose_conv<<<dim3(32, 24), 256, 0, stream>>>(W_emb,  WembT,  PD_,  DIM_);
    conv_bf16<<<1024, 256, 0, stream>>>(WQ, WQ_bf, (size_t)DIM_ * DIM_ / 4);
    conv_bf16<<<1024, 256, 0, stream>>>(WK, WK_bf, (size_t)DIM_ * DIM_ / 4);
    // WqkT[c,d] = sum_e WK[c,e] * WQ[d,e]   (A=WK_bf, BT=WQ_bf)
    gemm_bt_m128n64k64<true><<<dim3(DIM_ / 64, DIM_ / 128), 256, 0, stream>>>(
        WK_bf, WQ_bf, WqkT, nullptr, DIM_, DIM_, DIM_);
    transpose_conv<<<dim3(4, 4),   256, 0, stream>>>(WV,     WVT,    VDIM_, VDIM_);
    transpose_conv<<<dim3(32, 32), 256, 0, stream>>>(W_last, WlastT, DIM_, NC_);

    // --- stem ----------------------------------------------------------------
    patchify_ln<<<ROWS_, 256, 0, stream>>>(image, ln_p_g, ln_p_b, t_bf);
    gemm_bt_m128n64k64<true><<<dim3(DIM_ / 64, ROWS_ / 128), 256, 0, stream>>>(
        t_bf, WembT, h_bf, b_emb, ROWS_, DIM_, PD_);
    ln_rows<<<ROWS_ / 4, 256, 0, stream>>>(h_bf, x, ln_e_g, ln_e_b, pos);

    // --- zero A_pad + fwT once (40,894,464 B = 2,555,904 float4).
    // Guarantees: A_pad rows 196..223 stay zero; fwT k-cols 196..255 stay
    // zero (fw-gemm stores are col-masked <196) -> AV pad region is 0*0.
    zero_f4<<<2048, 256, 0, stream>>>((float4*)A_pad, (size_t)40894464 / 16);

    for (int layer = 0; layer < DEPTH_; layer++) {
        // h = LN(x)  (wave-per-row, XCD-clustered: av->x->ln->h->sfw L2 chain)
        ln_rows<<<ROWS_ / 4, 256, 0, stream>>>(x, h_bf, ln_g, ln_b, nullptr);
        // t = h @ Wqk   (128x64 tiles, BK=64, single-buffer)
        gemm_bt_m128n64k64<true><<<dim3(DIM_ / 64, ROWS_ / 128), 256, 0, stream>>>(
            h_bf, WqkT, t_bf, nullptr, ROWS_, DIM_, DIM_);
        // FUSED + XCD-clustered: S = scale*t@h^T (1024 items) + fwT (4096)
        sfw_fused<<<5120, 256, 0, stream>>>(t_bf, h_bf, S, WVT, fwT);
        // A_pad = softmax(S), XCD-clustered (same residue as producer/consumer)
        softmax_pad<<<832, 256, 0, stream>>>(S, A_pad);
        // x = A_pad @ fwT^T + h   (XCD-clustered 1D launch, 4096 items)
        av_gemm<<<4096, 256, 0, stream>>>(A_pad, fwT, x, h_bf);
    }

    pool_mean<<<dim3(B_, 4), 256, 0, stream>>>(x, pooled);
    gemm_bt_small64<false><<<dim3(16, 1, 1), 256, 0, stream>>>(
        pooled, 0, 0, DIM_, WlastT, 0, 0, DIM_, out, 0, 0, NC_,
        b_last, nullptr, 0, B_, NC_, DIM_, 1.0f, 1);
}

// Round 17
// 847.755 us; speedup vs baseline: 1.0301x; 1.0301x over previous
//
#include <hip/hip_runtime.h>
#include <stdint.h>

#define B_    64
#define C_    3
#define H_    224
#define W_    224
#define P_    16
#define GH_   14
#define NP_   196
#define NPP2_ 256          // AV contraction dim padded to 256 (BK=64 friendly)
#define PD_   768
#define HEADS_ 8
#define VDIM_ 128
#define DIM_  1024
#define DEPTH_ 6
#define NC_   1000
#define EPS_  1e-5f
#define SCALE_ 0.08838834764831845f   // 128^-0.5
#define ROWS_ (B_*NP_)                 // 12544
#define FTS2_ ((size_t)DIM_ * NPP2_)   // fwT per-batch stride (262144)
#define APS2_ ((size_t)224 * NPP2_)    // A_pad per-batch stride (57344)
#define XS_   ((size_t)NP_ * DIM_)     // h/t/x per-batch stride

typedef __bf16 bf16;
typedef __bf16 bfv8 __attribute__((ext_vector_type(8)));
typedef __bf16 bfv4 __attribute__((ext_vector_type(4)));
typedef float  f32x4 __attribute__((ext_vector_type(4)));

#define AS1 __attribute__((address_space(1)))
#define AS3 __attribute__((address_space(3)))

__device__ __forceinline__ void gld_lds16(const bf16* g, bf16* l) {
    __builtin_amdgcn_global_load_lds((const AS1 uint32_t*)g, (AS3 uint32_t*)l, 16, 0, 0);
}

__device__ __forceinline__ f32x4 mfma16(bfv8 a, bfv8 b, f32x4 c) {
    return __builtin_amdgcn_mfma_f32_16x16x32_bf16(a, b, c, 0, 0, 0);
}

// ---------------- zero-fill (float4 grid-stride) -----------------------------
__global__ void zero_f4(float4* __restrict__ p, size_t n4) {
    size_t i = (size_t)blockIdx.x * blockDim.x + threadIdx.x;
    size_t stride = (size_t)gridDim.x * blockDim.x;
    float4 z = {0.f, 0.f, 0.f, 0.f};
    for (; i < n4; i += stride) p[i] = z;
}

// ---------------- fp32 -> bf16 elementwise convert (x4 per thread) -----------
__global__ void conv_bf16(const float* __restrict__ in, bf16* __restrict__ out,
                          size_t n4) {
    size_t i = (size_t)blockIdx.x * blockDim.x + threadIdx.x;
    size_t stride = (size_t)gridDim.x * blockDim.x;
    for (; i < n4; i += stride) {
        float4 v = ((const float4*)in)[i];
        bfv4 o = { (bf16)v.x, (bf16)v.y, (bf16)v.z, (bf16)v.w };
        *(bfv4*)(out + i * 4) = o;
    }
}

// ---------------- block-wide twin reduction (patchify only) ------------------
__device__ inline void block_reduce_2(float& a, float& b) {
    __shared__ float sa[4], sb[4];
    #pragma unroll
    for (int o = 32; o > 0; o >>= 1) {
        a += __shfl_down(a, o);
        b += __shfl_down(b, o);
    }
    int lane = threadIdx.x & 63, wid = threadIdx.x >> 6;
    if (lane == 0) { sa[wid] = a; sb[wid] = b; }
    __syncthreads();
    a = sa[0] + sa[1] + sa[2] + sa[3];
    b = sb[0] + sb[1] + sb[2] + sb[3];
    __syncthreads();
}

// ---------------- patchify + LayerNorm over PD=768 -> bf16 -------------------
__global__ void patchify_ln(const float* __restrict__ img,
                            const float* __restrict__ g,
                            const float* __restrict__ beta,
                            bf16* __restrict__ out) {
    int bn = blockIdx.x;
    int b = bn / NP_, n = bn % NP_;
    int gh = n / GH_, gw = n % GH_;
    int t = threadIdx.x;              // pixel 0..255
    int p1 = t >> 4, p2 = t & 15;
    int row = gh * P_ + p1, col = gw * P_ + p2;
    const float* ip = img + (size_t)b * C_ * H_ * W_ + (size_t)row * W_ + col;
    float v0 = ip[0];
    float v1 = ip[H_ * W_];
    float v2 = ip[2 * H_ * W_];
    float s  = v0 + v1 + v2;
    float s2 = v0 * v0 + v1 * v1 + v2 * v2;
    block_reduce_2(s, s2);
    float mean = s * (1.0f / PD_);
    float var  = s2 * (1.0f / PD_) - mean * mean;
    float r = rsqrtf(var + EPS_);
    int d = t * 3;
    bf16* op = out + (size_t)bn * PD_ + d;
    op[0] = (bf16)((v0 - mean) * r * g[d]     + beta[d]);
    op[1] = (bf16)((v1 - mean) * r * g[d + 1] + beta[d + 1]);
    op[2] = (bf16)((v2 - mean) * r * g[d + 2] + beta[d + 2]);
}

// ---------------- row LayerNorm over DIM=1024: WAVE-PER-ROW ------------------
// (r10-proven, LINEAR block mapping — r16's XCD-clustered variant pinned each
// batch's h-slice in one L2 and slowed QK's cross-batch m-tiles by 9%; the
// round-robin distribution of h is load-bearing for QK. Do not cluster ln.)
__global__ void ln_rows(const bf16* __restrict__ in,
                        bf16* __restrict__ outb,
                        const float* __restrict__ g, const float* __restrict__ beta,
                        const float* __restrict__ pos) {
    int wave = threadIdx.x >> 6, lane = threadIdx.x & 63;
    int r = blockIdx.x * 4 + wave;
    const bf16* ip = in + (size_t)r * DIM_;
    float4 v[4];
    float s = 0.f, s2 = 0.f;
    #pragma unroll
    for (int i = 0; i < 4; i++) {
        bfv4 iv = *(const bfv4*)(ip + lane * 4 + i * 256);
        v[i].x = (float)iv[0]; v[i].y = (float)iv[1];
        v[i].z = (float)iv[2]; v[i].w = (float)iv[3];
        s  += v[i].x + v[i].y + v[i].z + v[i].w;
        s2 += v[i].x * v[i].x + v[i].y * v[i].y
            + v[i].z * v[i].z + v[i].w * v[i].w;
    }
    #pragma unroll
    for (int o = 32; o > 0; o >>= 1) {
        s  += __shfl_xor(s, o);
        s2 += __shfl_xor(s2, o);
    }
    float mean = s * (1.0f / DIM_);
    float var  = s2 * (1.0f / DIM_) - mean * mean;
    float rs = rsqrtf(var + EPS_);
    int n = r % NP_;
    bf16* op = outb + (size_t)r * DIM_;
    #pragma unroll
    for (int i = 0; i < 4; i++) {
        int idx = lane + i * 64;                 // float4 index into g/beta/pos
        float4 gv = ((const float4*)g)[idx];
        float4 bv = ((const float4*)beta)[idx];
        float4 o;
        o.x = (v[i].x - mean) * rs * gv.x + bv.x;
        o.y = (v[i].y - mean) * rs * gv.y + bv.y;
        o.z = (v[i].z - mean) * rs * gv.z + bv.z;
        o.w = (v[i].w - mean) * rs * gv.w + bv.w;
        if (pos) {
            float4 pv = ((const float4*)(pos + (size_t)n * DIM_))[idx];
            o.x += pv.x; o.y += pv.y; o.z += pv.z; o.w += pv.w;
        }
        bfv4 ob = { (bf16)o.x, (bf16)o.y, (bf16)o.z, (bf16)o.w };
        *(bfv4*)(op + lane * 4 + i * 256) = ob;
    }
}

// ---------------- 128x64-tile MFMA GEMM, BK=64, swizzled LDS -----------------
// (round-1 single-buffer version — measured ~640 TF. QK + stem + WqkT prep.)
template<bool OUT_BF16>
__global__ __launch_bounds__(256)
void gemm_bt_m128n64k64(const bf16* __restrict__ A, const bf16* __restrict__ BT,
                        void* __restrict__ Cout, const float* __restrict__ bias,
                        int M, int N, int K) {
    __shared__ bf16 Asm[128 * 64];   // 16 KB
    __shared__ bf16 Bsm[64 * 64];    //  8 KB
    const int tid = threadIdx.x;
    const int wave = tid >> 6, lane = tid & 63;
    const int MT = gridDim.y, NT = gridDim.x;
    const int flat = blockIdx.y * NT + blockIdx.x;
    const int per = 8 * NT;
    const int group = flat / per;
    const int within = flat % per;
    int gm = MT - group * 8; if (gm > 8) gm = 8;
    const int m0 = (group * 8 + within % gm) * 128;
    const int n0 = (within / gm) * 64;
    const int r8 = lane >> 3;
    const int cl = lane & 7;
    const int kg = (cl ^ r8) * 8;
    const bf16* Ag = A  + (size_t)(m0 + wave * 32 + r8) * K + kg;
    const bf16* Bg = BT + (size_t)(n0 + wave * 16 + r8) * K + kg;
    bf16* Al = Asm + wave * 2048;        // 32 rows x 64
    bf16* Bl = Bsm + wave * 1024;        // 16 rows x 64
    const int qd = lane >> 4, l15 = lane & 15;
    const int wm = (wave >> 1) * 64, wn = (wave & 1) * 32;
    f32x4 acc[4][2] = {};
    for (int k0 = 0; k0 < K; k0 += 64) {
        gld_lds16(Ag + k0,                 Al);
        gld_lds16(Ag + (size_t) 8 * K + k0, Al + 512);
        gld_lds16(Ag + (size_t)16 * K + k0, Al + 1024);
        gld_lds16(Ag + (size_t)24 * K + k0, Al + 1536);
        gld_lds16(Bg + k0,                 Bl);
        gld_lds16(Bg + (size_t) 8 * K + k0, Bl + 512);
        __syncthreads();
        bfv8 a0[4], a1[4], b0[2], b1[2];
        #pragma unroll
        for (int i = 0; i < 4; i++) {
            int R = wm + i * 16 + l15, sw = R & 7;
            a0[i] = *(const bfv8*)(Asm + R * 64 + ((qd    ) ^ sw) * 8);
            a1[i] = *(const bfv8*)(Asm + R * 64 + ((qd + 4) ^ sw) * 8);
        }
        #pragma unroll
        for (int j = 0; j < 2; j++) {
            int R = wn + j * 16 + l15, sw = R & 7;
            b0[j] = *(const bfv8*)(Bsm + R * 64 + ((qd    ) ^ sw) * 8);
            b1[j] = *(const bfv8*)(Bsm + R * 64 + ((qd + 4) ^ sw) * 8);
        }
        #pragma unroll
        for (int i = 0; i < 4; i++)
            #pragma unroll
            for (int j = 0; j < 2; j++) {
                acc[i][j] = mfma16(a0[i], b0[j], acc[i][j]);
                acc[i][j] = mfma16(a1[i], b1[j], acc[i][j]);
            }
        __syncthreads();
    }
    float* Cf = (float*)Cout;
    bf16*  Cb = (bf16*)Cout;
    #pragma unroll
    for (int i = 0; i < 4; i++) {
        int rowb = m0 + wm + i * 16 + qd * 4;
        #pragma unroll
        for (int j = 0; j < 2; j++) {
            int col = n0 + wn + j * 16 + l15;
            float bv = bias ? bias[col] : 0.0f;
            #pragma unroll
            for (int r = 0; r < 4; r++) {
                float v = acc[i][j][r] + bv;
                if (OUT_BF16) Cb[(size_t)(rowb + r) * N + col] = (bf16)v;
                else          Cf[(size_t)(rowb + r) * N + col] = v;
            }
        }
    }
}

// ---------------- small MFMA GEMM body: 64x64 tile, BK=64 --------------------
// (round-1-proven single-buffer structure, shared by all small-GEMM launchers.
// r14's 128-row-tile variant regressed even L2-hot — 64² + max block TLP is
// the confirmed optimum for these shapes; do not revisit.)
template<bool OUT_BF16>
__device__ __forceinline__ void small64_body(
        const bf16* __restrict__ A, long lda,
        const bf16* __restrict__ BT, long ldb,
        void* __restrict__ Cout, long ldc,
        const float* __restrict__ bias,
        const bf16* __restrict__ rs,
        int M, int N, int K, float alpha,
        int m0, int n0) {
    __shared__ bf16 Asm[64 * 64];
    __shared__ bf16 Bsm[64 * 64];
    const int tid = threadIdx.x;
    const int wave = tid >> 6, lane = tid & 63;
    const int r8 = lane >> 3;            // 0..7: row within 8-row staging group
    const int cl = lane & 7;             // LDS chunk within row
    const int kg = (cl ^ r8) * 8;        // global k-offset (bf16) for this lane
    const int qd = lane >> 4, l15 = lane & 15;
    const bf16* Ag0 = A  + (size_t)(m0 + wave * 16 + r8) * lda + kg;
    const bf16* Ag1 = Ag0 + (size_t)8 * lda;
    const bf16* Bg0 = BT + (size_t)(n0 + wave * 16 + r8) * ldb + kg;
    const bf16* Bg1 = Bg0 + (size_t)8 * ldb;
    bf16* Al0 = Asm + wave * 1024;       // 16 rows x 64
    bf16* Al1 = Al0 + 512;               // +8 rows
    bf16* Bl0 = Bsm + wave * 1024;
    bf16* Bl1 = Bl0 + 512;
    f32x4 acc[4] = {};
    for (int k0 = 0; k0 < K; k0 += 64) {
        gld_lds16(Ag0 + k0, Al0);
        gld_lds16(Ag1 + k0, Al1);
        gld_lds16(Bg0 + k0, Bl0);
        gld_lds16(Bg1 + k0, Bl1);
        __syncthreads();
        int RA = wave * 16 + l15, swa = RA & 7;
        bfv8 af0 = *(const bfv8*)(Asm + RA * 64 + ((qd    ) ^ swa) * 8);
        bfv8 af1 = *(const bfv8*)(Asm + RA * 64 + ((qd + 4) ^ swa) * 8);
        #pragma unroll
        for (int j = 0; j < 4; j++) {
            int R = j * 16 + l15, sw = R & 7;
            bfv8 b0 = *(const bfv8*)(Bsm + R * 64 + ((qd    ) ^ sw) * 8);
            bfv8 b1 = *(const bfv8*)(Bsm + R * 64 + ((qd + 4) ^ sw) * 8);
            acc[j] = mfma16(af0, b0, acc[j]);
            acc[j] = mfma16(af1, b1, acc[j]);
        }
        __syncthreads();
    }
    float* Cf = (float*)Cout;
    bf16*  Cb = (bf16*)Cout;
    #pragma unroll
    for (int j = 0; j < 4; j++) {
        int col = n0 + j * 16 + l15;
        if (col >= N) continue;
        float bv = bias ? bias[col] : 0.f;
        #pragma unroll
        for (int r = 0; r < 4; r++) {
            int row = m0 + wave * 16 + qd * 4 + r;
            if (row >= M) continue;
            float v = alpha * acc[j][r] + bv;
            if (rs) v += (float)rs[(size_t)row * ldc + col];
            if (OUT_BF16) Cb[(size_t)row * ldc + col] = (bf16)v;
            else          Cf[(size_t)row * ldc + col] = v;
        }
    }
}

// ---------------- small MFMA GEMM kernel (classifier) ------------------------
template<bool OUT_BF16>
__global__ __launch_bounds__(256)
void gemm_bt_small64(const bf16* __restrict__ A, long sA1, long sA2, long lda,
                     const bf16* __restrict__ BT, long sB1, long sB2, long ldb,
                     void* __restrict__ Cout, long sC1, long sC2, long ldc,
                     const float* __restrict__ bias,
                     const bf16* __restrict__ resid, long sR1,
                     int M, int N, int K, float alpha, int zdiv) {
    const int bz = blockIdx.z;
    const int z1 = bz / zdiv, z2 = bz % zdiv;
    small64_body<OUT_BF16>(
        A  + (size_t)z1 * sA1 + (size_t)z2 * sA2, lda,
        BT + (size_t)z1 * sB1 + (size_t)z2 * sB2, ldb,
        (void*)((OUT_BF16 ? (void*)((bf16*)Cout + (size_t)z1 * sC1 + (size_t)z2 * sC2)
                          : (void*)((float*)Cout + (size_t)z1 * sC1 + (size_t)z2 * sC2))),
        ldc, bias,
        resid ? resid + (size_t)z1 * sR1 : nullptr,
        M, N, K, alpha,
        blockIdx.y * 64, blockIdx.x * 64);
}

// ---------------- FUSED S + fw launch, XCD-batch-clustered -------------------
// (r13-exact.) xcd = id&7; batch z ≡ xcd mod 8 keeps each batch's t/h panels
// in one XCD L2. Per XCD: 128 S items + 512 fw items.
__global__ __launch_bounds__(256)
void sfw_fused(const bf16* __restrict__ t_bf, const bf16* __restrict__ h_bf,
               float* __restrict__ S, const bf16* __restrict__ WVT,
               bf16* __restrict__ fwT) {
    int b = blockIdx.x;                 // 5120
    int xcd = b & 7, idx = b >> 3;      // idx in [0,640)
    if (idx < 128) {
        // S-gemm: z = xcd + 8*(idx>>4), tile = idx&15 (bx=tile&3, by=tile>>2)
        int z = xcd + 8 * (idx >> 4);
        int tile = idx & 15;
        int bx = tile & 3, by = tile >> 2;
        small64_body<false>(
            t_bf + (size_t)z * XS_, DIM_,
            h_bf + (size_t)z * XS_, DIM_,
            (void*)(S + (size_t)z * (NP_ * NP_)), NP_,
            nullptr, nullptr,
            NP_, NP_, DIM_, SCALE_,
            by * 64, bx * 64);
    } else {
        // fw-gemm: f in [0,512): z1 = xcd + 8*(f>>6); r=f&63: head z2=r>>3,
        // tile t=r&7 (bx=t&3, by=t>>2)
        int f = idx - 128;
        int z1 = xcd + 8 * (f >> 6);
        int r = f & 63;
        int z2 = r >> 3;
        int t = r & 7;
        int bx = t & 3, by = t >> 2;
        small64_body<true>(
            WVT, VDIM_,
            h_bf + (size_t)z1 * XS_ + (size_t)z2 * VDIM_, DIM_,
            (void*)(fwT + (size_t)z1 * FTS2_ + (size_t)z2 * ((size_t)VDIM_ * NPP2_)),
            NPP2_,
            nullptr, nullptr,
            VDIM_, NP_, VDIM_, 1.0f,
            by * 64, bx * 64);
    }
}

// ---------------- AV GEMM launch, XCD-batch-clustered ------------------------
// (r13-exact.) x = A_pad @ fwT^T + h; each batch's 64 tiles on one XCD
// (fwT 512KB + A_pad 112KB L2-hot).
__global__ __launch_bounds__(256)
void av_gemm(const bf16* __restrict__ A_pad, const bf16* __restrict__ fwT,
             bf16* __restrict__ x, const bf16* __restrict__ h_bf) {
    int b = blockIdx.x;                 // 4096
    int xcd = b & 7, idx = b >> 3;      // idx in [0,512)
    int z = xcd + 8 * (idx >> 6);       // batch
    int r = idx & 63;
    int by = r >> 4, bx = r & 15;       // m-tile 0..3, n-tile 0..15
    small64_body<true>(
        A_pad + (size_t)z * APS2_, NPP2_,
        fwT   + (size_t)z * FTS2_, NPP2_,
        (void*)(x + (size_t)z * XS_), DIM_,
        nullptr,
        h_bf + (size_t)z * XS_,
        NP_, DIM_, NPP2_, 1.0f,
        by * 64, bx * 64);
}

// ------- softmax, XCD-batch-clustered: fp32 S -> bf16 A_pad [b][224][256] ----
// (r15-proven.) Same residue mapping as S-producer / A_pad-consumer.
// 832 blocks = 8 xcd x 8 batches x 13 chunks of 16 rows.
__global__ void softmax_pad(const float* __restrict__ S, bf16* __restrict__ Apad) {
    int b = blockIdx.x;                 // 832
    int xcd = b & 7, idx = b >> 3;      // idx in [0,104)
    int z = xcd + 8 * (idx / 13);       // batch
    int c = idx % 13;                   // 16-row chunk
    int wave = threadIdx.x >> 6, lane = threadIdx.x & 63;
    int base = c * 16 + wave * 4;
    const float* Sb = S + (size_t)z * (NP_ * NP_);
    bf16* Pb = Apad + (size_t)z * APS2_;
    #pragma unroll
    for (int i = 0; i < 4; i++) {
        int n = base + i;
        if (n >= NP_) continue;
        const float* Sp = Sb + (size_t)n * NP_;
        float v0 = Sp[lane];
        float v1 = Sp[lane + 64];
        float v2 = Sp[lane + 128];
        float v3 = (lane < NP_ - 192) ? Sp[lane + 192] : -1e30f;
        float mx = fmaxf(fmaxf(v0, v1), fmaxf(v2, v3));
        #pragma unroll
        for (int o = 32; o > 0; o >>= 1) mx = fmaxf(mx, __shfl_xor(mx, o));
        float e0 = __expf(v0 - mx);
        float e1 = __expf(v1 - mx);
        float e2 = __expf(v2 - mx);
        float e3 = (lane < NP_ - 192) ? __expf(v3 - mx) : 0.f;
        float s = e0 + e1 + e2 + e3;
        #pragma unroll
        for (int o = 32; o > 0; o >>= 1) s += __shfl_xor(s, o);
        float inv = 1.0f / s;
        bf16* Pr = Pb + (size_t)n * NPP2_;
        Pr[lane]       = (bf16)(e0 * inv);
        Pr[lane + 64]  = (bf16)(e1 * inv);
        Pr[lane + 128] = (bf16)(e2 * inv);
        int c3 = lane + 192;
        Pr[c3] = (c3 < NP_) ? (bf16)(e3 * inv) : (bf16)0.f;
    }
}

// ---------------- transpose+convert fp32 [R,C] -> bf16 [C,R] -----------------
__global__ void transpose_conv(const float* __restrict__ in, bf16* __restrict__ out,
                               int R, int Cc) {
    __shared__ float t[32][33];
    int c0 = blockIdx.x * 32, r0 = blockIdx.y * 32;
    int tx = threadIdx.x & 31, ty = threadIdx.x >> 5;   // 32 x 8
    #pragma unroll
    for (int i = 0; i < 4; i++) {
        int r = r0 + ty + i * 8;
        if (r < R && c0 + tx < Cc) t[ty + i * 8][tx] = in[(size_t)r * Cc + c0 + tx];
    }
    __syncthreads();
    #pragma unroll
    for (int i = 0; i < 4; i++) {
        int c = c0 + ty + i * 8, r = r0 + tx;
        if (c < Cc && r < R) out[(size_t)c * R + r] = (bf16)t[tx][ty + i * 8];
    }
}

// ---------------- mean-pool over 196 patches: bf16 in -> bf16 out ------------
__global__ void pool_mean(const bf16* __restrict__ x, bf16* __restrict__ pooled) {
    int b = blockIdx.x;
    int d = blockIdx.y * 256 + threadIdx.x;
    const bf16* p = x + (size_t)b * NP_ * DIM_ + d;
    float s = 0.f;
    for (int n = 0; n < NP_; n++) s += (float)p[(size_t)n * DIM_];
    pooled[(size_t)b * DIM_ + d] = (bf16)(s * (1.0f / NP_));
}

// =============================================================================
extern "C" void kernel_launch(void* const* d_in, const int* in_sizes, int n_in,
                              void* d_out, int out_size, void* d_ws, size_t ws_size,
                              hipStream_t stream) {
    const float* image  = (const float*)d_in[0];
    const float* pos    = (const float*)d_in[1];
    const float* ln_p_g = (const float*)d_in[2];
    const float* ln_p_b = (const float*)d_in[3];
    const float* W_emb  = (const float*)d_in[4];
    const float* b_emb  = (const float*)d_in[5];
    const float* ln_e_g = (const float*)d_in[6];
    const float* ln_e_b = (const float*)d_in[7];
    const float* WV     = (const float*)d_in[8];
    const float* WK     = (const float*)d_in[9];
    const float* WQ     = (const float*)d_in[10];
    const float* ln_g   = (const float*)d_in[11];
    const float* ln_b   = (const float*)d_in[12];
    const float* W_last = (const float*)d_in[13];
    const float* b_last = (const float*)d_in[14];
    float* out = (float*)d_out;

    char* p = (char*)d_ws;
    auto alloc = [&](size_t bytes) { char* r = p; p += (bytes + 255) & ~(size_t)255; return r; };
    // x: bf16 residual stream [12544,1024]
    bf16*  x = (bf16*)alloc((size_t)ROWS_ * DIM_ * 2);
    // attention region: S (fp32) | A_pad [64][224][256] | fwT [64][1024][256].
    // Adjacency required: AV A-staging tail (batch 63, m-tile 3) reads <=16KB
    // past A_pad end into fwT (finite; output rows masked).
    char*  region = alloc(9834496 + 7340032 + 33554432);
    float* S     = (float*)region;                              //  9,834,496 B
    bf16*  A_pad = (bf16*)(region + 9834496);                   //  7,340,032 B
    bf16*  fwT   = (bf16*)(region + 9834496 + 7340032);         // 33,554,432 B
    // ORDER AUDIT (gld staging overruns): S-gemm B-tail reads <=123 KB past
    // h_bf (into t_bf); S-gemm A-tail <=123 KB past t_bf (into WembT); fw-gemm
    // B-tail past h_bf (into t_bf); AV A-tail <=16 KB past A_pad (into fwT);
    // classifier N-tail <=49 KB past WlastT (into pooled). Keep this order.
    bf16*  h_bf  = (bf16*)alloc((size_t)ROWS_ * DIM_ * 2);
    bf16*  t_bf  = (bf16*)alloc((size_t)ROWS_ * DIM_ * 2);
    bf16*  WembT  = (bf16*)alloc((size_t)DIM_ * PD_ * 2);
    bf16*  WQ_bf  = (bf16*)alloc((size_t)DIM_ * DIM_ * 2);     // untransposed bf16
    bf16*  WK_bf  = (bf16*)alloc((size_t)DIM_ * DIM_ * 2);
    bf16*  WqkT   = (bf16*)alloc((size_t)DIM_ * DIM_ * 2);     // (WQ WK^T)^T = WK WQ^T
    bf16*  WVT    = (bf16*)alloc((size_t)VDIM_ * VDIM_ * 2);
    bf16*  WlastT = (bf16*)alloc((size_t)NC_ * DIM_ * 2);
    bf16*  pooled = (bf16*)alloc((size_t)B_ * DIM_ * 2);

    // --- weight prep, once per call ------------------------------------------
    transpose_conv<<<dim3(32, 24), 256, 0, stream>>>(W_emb,  WembT,  PD_,  DIM_);
    conv_bf16<<<1024, 256, 0, stream>>>(WQ, WQ_bf, (size_t)DIM_ * DIM_ / 4);
    conv_bf16<<<1024, 256, 0, stream>>>(WK, WK_bf, (size_t)DIM_ * DIM_ / 4);
    // WqkT[c,d] = sum_e WK[c,e] * WQ[d,e]   (A=WK_bf, BT=WQ_bf)
    gemm_bt_m128n64k64<true><<<dim3(DIM_ / 64, DIM_ / 128), 256, 0, stream>>>(
        WK_bf, WQ_bf, WqkT, nullptr, DIM_, DIM_, DIM_);
    transpose_conv<<<dim3(4, 4),   256, 0, stream>>>(WV,     WVT,    VDIM_, VDIM_);
    transpose_conv<<<dim3(32, 32), 256, 0, stream>>>(W_last, WlastT, DIM_, NC_);

    // --- stem ----------------------------------------------------------------
    patchify_ln<<<ROWS_, 256, 0, stream>>>(image, ln_p_g, ln_p_b, t_bf);
    gemm_bt_m128n64k64<true><<<dim3(DIM_ / 64, ROWS_ / 128), 256, 0, stream>>>(
        t_bf, WembT, h_bf, b_emb, ROWS_, DIM_, PD_);
    ln_rows<<<ROWS_ / 4, 256, 0, stream>>>(h_bf, x, ln_e_g, ln_e_b, pos);

    // --- zero A_pad + fwT once (40,894,464 B = 2,555,904 float4).
    // Guarantees: A_pad rows 196..223 stay zero; fwT k-cols 196..255 stay
    // zero (fw-gemm stores are col-masked <196) -> AV pad region is 0*0.
    zero_f4<<<2048, 256, 0, stream>>>((float4*)A_pad, (size_t)40894464 / 16);

    for (int layer = 0; layer < DEPTH_; layer++) {
        // h = LN(x)  (wave-per-row, linear mapping — load-bearing for QK)
        ln_rows<<<ROWS_ / 4, 256, 0, stream>>>(x, h_bf, ln_g, ln_b, nullptr);
        // t = h @ Wqk   (128x64 tiles, BK=64, single-buffer)
        gemm_bt_m128n64k64<true><<<dim3(DIM_ / 64, ROWS_ / 128), 256, 0, stream>>>(
            h_bf, WqkT, t_bf, nullptr, ROWS_, DIM_, DIM_);
        // FUSED + XCD-clustered: S = scale*t@h^T (1024 items) + fwT (4096)
        sfw_fused<<<5120, 256, 0, stream>>>(t_bf, h_bf, S, WVT, fwT);
        // A_pad = softmax(S), XCD-clustered (same residue as producer/consumer)
        softmax_pad<<<832, 256, 0, stream>>>(S, A_pad);
        // x = A_pad @ fwT^T + h   (XCD-clustered 1D launch, 4096 items)
        av_gemm<<<4096, 256, 0, stream>>>(A_pad, fwT, x, h_bf);
    }

    pool_mean<<<dim3(B_, 4), 256, 0, stream>>>(x, pooled);
    gemm_bt_small64<false><<<dim3(16, 1, 1), 256, 0, stream>>>(
        pooled, 0, 0, DIM_, WlastT, 0, 0, DIM_, out, 0, 0, NC_,
        b_last, nullptr, 0, B_, NC_, DIM_, 1.0f, 1);
}